// Round 1
// baseline (423.078 us; speedup 1.0000x reference)
//
#include <hip/hip_runtime.h>
#include <hip/hip_bf16.h>

// Problem constants (static: N and candidate set are compile-time in the reference)
#define N_TOTAL 56770560            // 55440 * 1024
#define PCOLS   110880              // lcm of all candidate lengths = 2^5*3^2*5*7*11
#define NROWS   512                 // N_TOTAL / PCOLS
#define C4      27720               // PCOLS / 4 (float4 columns)
#define NLENS   20

__constant__ int kLens[NLENS] = {4,5,6,7,8,9,10,11,12,14,15,16,18,20,21,22,24,28,30,32};

// ---------------------------------------------------------------------------
// Pass 1: per-column (residue mod PCOLS) min/max over a chunk of rows.
// x viewed as [NROWS][PCOLS]; each thread owns 4 consecutive columns (float4).
// grid = (ceil(C4/256), RC); partials are [RC][PCOLS] for max and min.
// ---------------------------------------------------------------------------
__global__ __launch_bounds__(256) void colminmax_kernel(
    const float4* __restrict__ x, float* __restrict__ pmax,
    float* __restrict__ pmin, int rowsPerChunk) {
  int c4 = blockIdx.x * 256 + threadIdx.x;
  if (c4 >= C4) return;
  int chunk = blockIdx.y;
  const float4* p = x + (size_t)chunk * rowsPerChunk * C4 + c4;

  float4 vmx = make_float4(-3.402823466e38f, -3.402823466e38f,
                           -3.402823466e38f, -3.402823466e38f);
  float4 vmn = make_float4(3.402823466e38f, 3.402823466e38f,
                           3.402823466e38f, 3.402823466e38f);
#pragma unroll 4
  for (int r = 0; r < rowsPerChunk; ++r) {
    float4 v = p[(size_t)r * C4];
    vmx.x = fmaxf(vmx.x, v.x); vmn.x = fminf(vmn.x, v.x);
    vmx.y = fmaxf(vmx.y, v.y); vmn.y = fminf(vmn.y, v.y);
    vmx.z = fmaxf(vmx.z, v.z); vmn.z = fminf(vmn.z, v.z);
    vmx.w = fmaxf(vmx.w, v.w); vmn.w = fminf(vmn.w, v.w);
  }
  ((float4*)(pmax + (size_t)chunk * PCOLS))[c4] = vmx;
  ((float4*)(pmin + (size_t)chunk * PCOLS))[c4] = vmn;
}

// ---------------------------------------------------------------------------
// Pass 2: fold RC partial chunks -> final per-residue Mx/Mn.
// ---------------------------------------------------------------------------
__global__ __launch_bounds__(256) void fold_kernel(
    const float* __restrict__ pmax, const float* __restrict__ pmin,
    float* __restrict__ Mx, float* __restrict__ Mn, int RC) {
  int r = blockIdx.x * 256 + threadIdx.x;
  if (r >= PCOLS) return;
  float mx = pmax[r], mn = pmin[r];
  for (int c = 1; c < RC; ++c) {
    mx = fmaxf(mx, pmax[(size_t)c * PCOLS + r]);
    mn = fminf(mn, pmin[(size_t)c * PCOLS + r]);
  }
  Mx[r] = mx;
  Mn[r] = mn;
}

// ---------------------------------------------------------------------------
// Pass 3: one block per candidate length. md_L = max_r max(Mx[r]-p, p-Mn[r])
// with p = x[r mod L]. Incremental residue tracking (no integer div in loop).
// Writes out[k] = max_diffs[k], out[20+k] = eff_scores[k].
// ---------------------------------------------------------------------------
__global__ __launch_bounds__(256) void md_kernel(
    const float* __restrict__ x, const float* __restrict__ Mx,
    const float* __restrict__ Mn, float* __restrict__ out) {
  __shared__ float pat[32];
  __shared__ float red[4];
  const int tid = threadIdx.x;
  const int L = kLens[blockIdx.x];
  if (tid < 32) pat[tid] = x[tid];
  __syncthreads();

  int s = 256 % L;        // stride between this thread's successive residues
  int rm = tid % L;       // one mod at entry only
  float acc = 0.0f;       // true md >= 0 always (class r contains x[r] for r<L)
  for (int r = tid; r < PCOLS; r += 256) {
    float p = pat[rm];
    float a = Mx[r] - p;
    float b = p - Mn[r];
    acc = fmaxf(acc, fmaxf(a, b));
    rm += s;
    if (rm >= L) rm -= L;
  }
  // wave (64-lane) reduce, then cross-wave via LDS
#pragma unroll
  for (int off = 32; off > 0; off >>= 1)
    acc = fmaxf(acc, __shfl_down(acc, off, 64));
  if ((tid & 63) == 0) red[tid >> 6] = acc;
  __syncthreads();
  if (tid == 0) {
    float md = fmaxf(fmaxf(red[0], red[1]), fmaxf(red[2], red[3]));
    out[blockIdx.x] = md;
    // raw score exactly as python: float(n // L) / float(L) in double, cast f32
    double raw = (double)(N_TOTAL / L) / (double)L;
    out[NLENS + blockIdx.x] = (md < 0.01f) ? (float)raw : 0.0f;
  }
}

// ---------------------------------------------------------------------------
// Pass 4: first-occurrence argmax over eff_scores -> best_idx, best_score.
// ---------------------------------------------------------------------------
__global__ void fin_kernel(float* __restrict__ out) {
  if (threadIdx.x == 0 && blockIdx.x == 0) {
    float best = out[NLENS];
    int bi = 0;
    for (int k = 1; k < NLENS; ++k) {
      float e = out[NLENS + k];
      if (e > best) { best = e; bi = k; }   // strict > keeps first max (jnp.argmax)
    }
    out[2 * NLENS] = (float)bi;
    out[2 * NLENS + 1] = best;
  }
}

extern "C" void kernel_launch(void* const* d_in, const int* in_sizes, int n_in,
                              void* d_out, int out_size, void* d_ws, size_t ws_size,
                              hipStream_t stream) {
  const float* x = (const float*)d_in[0];
  float* out = (float*)d_out;

  // Pick row-chunk count RC based on available workspace.
  // ws layout: Mx[PCOLS] | Mn[PCOLS] | pmax[RC*PCOLS] | pmin[RC*PCOLS]
  int RC = 8;
  while (RC > 1 && ws_size < (size_t)(2 + 2 * RC) * PCOLS * sizeof(float)) RC >>= 1;
  int rowsPerChunk = NROWS / RC;

  float* Mx   = (float*)d_ws;
  float* Mn   = Mx + PCOLS;
  float* pmax = Mn + PCOLS;
  float* pmin = pmax + (size_t)RC * PCOLS;

  dim3 grid1((C4 + 255) / 256, RC);
  colminmax_kernel<<<grid1, 256, 0, stream>>>((const float4*)x, pmax, pmin,
                                              rowsPerChunk);
  fold_kernel<<<(PCOLS + 255) / 256, 256, 0, stream>>>(pmax, pmin, Mx, Mn, RC);
  md_kernel<<<NLENS, 256, 0, stream>>>(x, Mx, Mn, out);
  fin_kernel<<<1, 64, 0, stream>>>(out);
}

// Round 3
// 318.265 us; speedup vs baseline: 1.3293x; 1.3293x over previous
//
#include <hip/hip_runtime.h>
#include <hip/hip_bf16.h>

// Problem constants (static: N and candidate set are compile-time in the reference)
#define N_TOTAL 56770560            // 55440 * 1024
#define PCOLS   110880              // lcm of all candidate lengths = 2^5*3^2*5*7*11
#define NROWS   512                 // N_TOTAL / PCOLS
#define C4      27720               // PCOLS / 4 (float4 columns)
#define NLENS   20
#define SPL     16                  // md_kernel splits per candidate length
#define SPAN    (PCOLS / SPL)       // 6930 residues per md block

__constant__ int kLens[NLENS] = {4,5,6,7,8,9,10,11,12,14,15,16,18,20,21,22,24,28,30,32};

// ---------------------------------------------------------------------------
// Pass 1: per-column (residue mod PCOLS) min/max over a chunk of rows.
// x viewed as [NROWS][PCOLS]; each thread owns 4 consecutive columns (float4).
// grid = (ceil(C4/256), RC); partials are [RC][PCOLS] for max and min.
// ---------------------------------------------------------------------------
__global__ __launch_bounds__(256) void colminmax_kernel(
    const float4* __restrict__ x, float* __restrict__ pmax,
    float* __restrict__ pmin, int rowsPerChunk) {
  int c4 = blockIdx.x * 256 + threadIdx.x;
  if (c4 >= C4) return;
  int chunk = blockIdx.y;
  const float4* p = x + (size_t)chunk * rowsPerChunk * C4 + c4;

  float4 vmx = make_float4(-3.402823466e38f, -3.402823466e38f,
                           -3.402823466e38f, -3.402823466e38f);
  float4 vmn = make_float4(3.402823466e38f, 3.402823466e38f,
                           3.402823466e38f, 3.402823466e38f);
#pragma unroll 8
  for (int r = 0; r < rowsPerChunk; ++r) {
    float4 v = p[(size_t)r * C4];
    vmx.x = fmaxf(vmx.x, v.x); vmn.x = fminf(vmn.x, v.x);
    vmx.y = fmaxf(vmx.y, v.y); vmn.y = fminf(vmn.y, v.y);
    vmx.z = fmaxf(vmx.z, v.z); vmn.z = fminf(vmn.z, v.z);
    vmx.w = fmaxf(vmx.w, v.w); vmn.w = fminf(vmn.w, v.w);
  }
  ((float4*)(pmax + (size_t)chunk * PCOLS))[c4] = vmx;
  ((float4*)(pmin + (size_t)chunk * PCOLS))[c4] = vmn;
}

// ---------------------------------------------------------------------------
// Pass 2: fold RC partial chunks -> final per-residue Mx/Mn.
// ---------------------------------------------------------------------------
__global__ __launch_bounds__(256) void fold_kernel(
    const float* __restrict__ pmax, const float* __restrict__ pmin,
    float* __restrict__ Mx, float* __restrict__ Mn, int RC) {
  int r = blockIdx.x * 256 + threadIdx.x;
  if (r >= PCOLS) return;
  float mx = pmax[r], mn = pmin[r];
  for (int c = 1; c < RC; ++c) {
    mx = fmaxf(mx, pmax[(size_t)c * PCOLS + r]);
    mn = fminf(mn, pmin[(size_t)c * PCOLS + r]);
  }
  Mx[r] = mx;
  Mn[r] = mn;
}

// ---------------------------------------------------------------------------
// Pass 3: grid (SPL, NLENS). Block (b, k) covers residues [b*SPAN, (b+1)*SPAN)
// for L = kLens[k]:  partial_md = max_r max(Mx[r]-p, p-Mn[r]),  p = x[r mod L].
// Incremental residue tracking (no integer div in loop). Partials -> mdpart.
// ---------------------------------------------------------------------------
__global__ __launch_bounds__(256) void md_kernel(
    const float* __restrict__ x, const float* __restrict__ Mx,
    const float* __restrict__ Mn, float* __restrict__ mdpart) {
  __shared__ float pat[32];
  __shared__ float red[4];
  const int tid = threadIdx.x;
  const int L = kLens[blockIdx.y];
  const int base = blockIdx.x * SPAN;
  if (tid < 32) pat[tid] = x[tid];
  __syncthreads();

  int s = 256 % L;              // stride between successive residues of a thread
  int rm = (base + tid) % L;    // one mod at entry only
  float acc = 0.0f;             // true md >= 0 always (i = i mod L gives 0)
#pragma unroll 4
  for (int r = base + tid; r < base + SPAN; r += 256) {
    float p = pat[rm];
    acc = fmaxf(acc, fmaxf(Mx[r] - p, p - Mn[r]));
    rm += s;
    if (rm >= L) rm -= L;
  }
  // wave (64-lane) reduce, then cross-wave via LDS
#pragma unroll
  for (int off = 32; off > 0; off >>= 1)
    acc = fmaxf(acc, __shfl_down(acc, off, 64));
  if ((tid & 63) == 0) red[tid >> 6] = acc;
  __syncthreads();
  if (tid == 0) {
    mdpart[blockIdx.y * SPL + blockIdx.x] =
        fmaxf(fmaxf(red[0], red[1]), fmaxf(red[2], red[3]));
  }
}

// ---------------------------------------------------------------------------
// Pass 4: fold SPL partials per length, gate scores, first-occurrence argmax.
// out[0..19] = max_diffs, out[20..39] = eff_scores, out[40] = best_idx,
// out[41] = best_score.
// ---------------------------------------------------------------------------
__global__ void fin_kernel(const float* __restrict__ mdpart,
                           float* __restrict__ out) {
  __shared__ float eff_s[NLENS];
  const int k = threadIdx.x;
  if (k < NLENS) {
    float md = 0.0f;
#pragma unroll
    for (int j = 0; j < SPL; ++j) md = fmaxf(md, mdpart[k * SPL + j]);
    out[k] = md;
    // raw score exactly as python: float(n // L) / float(L) in double, cast f32
    const int L = kLens[k];
    double raw = (double)(N_TOTAL / L) / (double)L;
    float eff = (md < 0.01f) ? (float)raw : 0.0f;
    out[NLENS + k] = eff;
    eff_s[k] = eff;
  }
  __syncthreads();
  if (k == 0) {
    float best = eff_s[0];
    int bi = 0;
    for (int i = 1; i < NLENS; ++i) {
      if (eff_s[i] > best) { best = eff_s[i]; bi = i; }  // strict >: first max
    }
    out[2 * NLENS] = (float)bi;
    out[2 * NLENS + 1] = best;
  }
}

extern "C" void kernel_launch(void* const* d_in, const int* in_sizes, int n_in,
                              void* d_out, int out_size, void* d_ws, size_t ws_size,
                              hipStream_t stream) {
  const float* x = (const float*)d_in[0];
  float* out = (float*)d_out;

  // Pick row-chunk count RC based on available workspace.
  // ws layout: Mx[PCOLS] | Mn[PCOLS] | pmax[RC*PCOLS] | pmin[RC*PCOLS] | mdpart
  int RC = 8;
  while (RC > 1 &&
         ws_size < (size_t)(2 + 2 * RC) * PCOLS * sizeof(float) +
                       (size_t)NLENS * SPL * sizeof(float))
    RC >>= 1;
  int rowsPerChunk = NROWS / RC;

  float* Mx     = (float*)d_ws;
  float* Mn     = Mx + PCOLS;
  float* pmax   = Mn + PCOLS;
  float* pmin   = pmax + (size_t)RC * PCOLS;
  float* mdpart = pmin + (size_t)RC * PCOLS;

  dim3 grid1((C4 + 255) / 256, RC);
  colminmax_kernel<<<grid1, 256, 0, stream>>>((const float4*)x, pmax, pmin,
                                              rowsPerChunk);
  fold_kernel<<<(PCOLS + 255) / 256, 256, 0, stream>>>(pmax, pmin, Mx, Mn, RC);
  dim3 grid3(SPL, NLENS);
  md_kernel<<<grid3, 256, 0, stream>>>(x, Mx, Mn, mdpart);
  fin_kernel<<<1, 64, 0, stream>>>(mdpart, out);
}

// Round 6
// 298.118 us; speedup vs baseline: 1.4192x; 1.0676x over previous
//
#include <hip/hip_runtime.h>
#include <hip/hip_bf16.h>

// Problem constants (static: N and candidate set are compile-time in the reference)
#define N_TOTAL 56770560            // 55440 * 1024
#define PCOLS   110880              // lcm of all candidate lengths = 2^5*3^2*5*7*11
#define NROWS   512                 // N_TOTAL / PCOLS
#define C4      27720               // PCOLS / 4 (float4 columns)
#define NLENS   20
#define SPL     16                  // md_kernel splits per candidate length
#define SPAN    (PCOLS / SPL)       // 6930 residues per md block
#define RC      16                  // row chunks for pass 1 (1744 blocks)

// Native clang vector type: layout-compatible with float4, accepted by
// __builtin_nontemporal_load (HIP_vector_type struct is NOT).
typedef float floatx4 __attribute__((ext_vector_type(4)));

__constant__ int kLens[NLENS] = {4,5,6,7,8,9,10,11,12,14,15,16,18,20,21,22,24,28,30,32};

// ---------------------------------------------------------------------------
// Pass 1: per-column (residue mod PCOLS) min/max over a chunk of rows.
// x viewed as [NROWS][PCOLS]; each thread owns 4 consecutive columns (float4).
// grid = (ceil(C4/256), RC); partials are [RC][PCOLS] for max and min.
// Input is read exactly once -> non-temporal loads (don't pollute L2/L3).
// ---------------------------------------------------------------------------
__global__ __launch_bounds__(256) void colminmax_kernel(
    const floatx4* __restrict__ x, float* __restrict__ pmax,
    float* __restrict__ pmin) {
  const int rowsPerChunk = NROWS / RC;   // 32
  int c4 = blockIdx.x * 256 + threadIdx.x;
  if (c4 >= C4) return;
  int chunk = blockIdx.y;
  const floatx4* p = x + (size_t)chunk * rowsPerChunk * C4 + c4;

  floatx4 vmx = {-3.402823466e38f, -3.402823466e38f,
                 -3.402823466e38f, -3.402823466e38f};
  floatx4 vmn = {3.402823466e38f, 3.402823466e38f,
                 3.402823466e38f, 3.402823466e38f};
#pragma unroll 8
  for (int r = 0; r < rowsPerChunk; ++r) {
    floatx4 v = __builtin_nontemporal_load(&p[(size_t)r * C4]);
    vmx.x = fmaxf(vmx.x, v.x); vmn.x = fminf(vmn.x, v.x);
    vmx.y = fmaxf(vmx.y, v.y); vmn.y = fminf(vmn.y, v.y);
    vmx.z = fmaxf(vmx.z, v.z); vmn.z = fminf(vmn.z, v.z);
    vmx.w = fmaxf(vmx.w, v.w); vmn.w = fminf(vmn.w, v.w);
  }
  ((floatx4*)(pmax + (size_t)chunk * PCOLS))[c4] = vmx;
  ((floatx4*)(pmin + (size_t)chunk * PCOLS))[c4] = vmn;
}

// ---------------------------------------------------------------------------
// Pass 2: fold RC partial chunks -> final per-residue Mx/Mn.
// ---------------------------------------------------------------------------
__global__ __launch_bounds__(256) void fold_kernel(
    const float* __restrict__ pmax, const float* __restrict__ pmin,
    float* __restrict__ Mx, float* __restrict__ Mn) {
  int r = blockIdx.x * 256 + threadIdx.x;
  if (r >= PCOLS) return;
  float mx = pmax[r], mn = pmin[r];
#pragma unroll
  for (int c = 1; c < RC; ++c) {
    mx = fmaxf(mx, pmax[(size_t)c * PCOLS + r]);
    mn = fminf(mn, pmin[(size_t)c * PCOLS + r]);
  }
  Mx[r] = mx;
  Mn[r] = mn;
}

// ---------------------------------------------------------------------------
// Pass 3: grid (SPL, NLENS). Block (b, k) covers residues [b*SPAN, (b+1)*SPAN)
// for L = kLens[k]:  partial_md = max_r max(Mx[r]-p, p-Mn[r]),  p = x[r mod L].
// Incremental residue tracking (no integer div in loop). Partials -> mdpart.
// ---------------------------------------------------------------------------
__global__ __launch_bounds__(256) void md_kernel(
    const float* __restrict__ x, const float* __restrict__ Mx,
    const float* __restrict__ Mn, float* __restrict__ mdpart) {
  __shared__ float pat[32];
  __shared__ float red[4];
  const int tid = threadIdx.x;
  const int L = kLens[blockIdx.y];
  const int base = blockIdx.x * SPAN;
  if (tid < 32) pat[tid] = x[tid];
  __syncthreads();

  int s = 256 % L;              // stride between successive residues of a thread
  int rm = (base + tid) % L;    // one mod at entry only
  float acc = 0.0f;             // true md >= 0 always (i = i mod L gives 0)
#pragma unroll 5
  for (int r = base + tid; r < base + SPAN; r += 256) {
    float p = pat[rm];
    acc = fmaxf(acc, fmaxf(Mx[r] - p, p - Mn[r]));
    rm += s;
    if (rm >= L) rm -= L;
  }
  // wave (64-lane) reduce, then cross-wave via LDS
#pragma unroll
  for (int off = 32; off > 0; off >>= 1)
    acc = fmaxf(acc, __shfl_down(acc, off, 64));
  if ((tid & 63) == 0) red[tid >> 6] = acc;
  __syncthreads();
  if (tid == 0) {
    mdpart[blockIdx.y * SPL + blockIdx.x] =
        fmaxf(fmaxf(red[0], red[1]), fmaxf(red[2], red[3]));
  }
}

// ---------------------------------------------------------------------------
// Pass 4: fold SPL partials per length, gate scores, first-occurrence argmax.
// out[0..19] = max_diffs, out[20..39] = eff_scores, out[40] = best_idx,
// out[41] = best_score.
// ---------------------------------------------------------------------------
__global__ void fin_kernel(const float* __restrict__ mdpart,
                           float* __restrict__ out) {
  __shared__ float eff_s[NLENS];
  const int k = threadIdx.x;
  if (k < NLENS) {
    float md = 0.0f;
#pragma unroll
    for (int j = 0; j < SPL; ++j) md = fmaxf(md, mdpart[k * SPL + j]);
    out[k] = md;
    // raw score exactly as python: float(n // L) / float(L) in double, cast f32
    const int L = kLens[k];
    double raw = (double)(N_TOTAL / L) / (double)L;
    float eff = (md < 0.01f) ? (float)raw : 0.0f;
    out[NLENS + k] = eff;
    eff_s[k] = eff;
  }
  __syncthreads();
  if (k == 0) {
    float best = eff_s[0];
    int bi = 0;
    for (int i = 1; i < NLENS; ++i) {
      if (eff_s[i] > best) { best = eff_s[i]; bi = i; }  // strict >: first max
    }
    out[2 * NLENS] = (float)bi;
    out[2 * NLENS + 1] = best;
  }
}

extern "C" void kernel_launch(void* const* d_in, const int* in_sizes, int n_in,
                              void* d_out, int out_size, void* d_ws, size_t ws_size,
                              hipStream_t stream) {
  const float* x = (const float*)d_in[0];
  float* out = (float*)d_out;

  // ws layout: Mx[PCOLS] | Mn[PCOLS] | pmax[RC*PCOLS] | pmin[RC*PCOLS] | mdpart
  float* Mx     = (float*)d_ws;
  float* Mn     = Mx + PCOLS;
  float* pmax   = Mn + PCOLS;
  float* pmin   = pmax + (size_t)RC * PCOLS;
  float* mdpart = pmin + (size_t)RC * PCOLS;

  dim3 grid1((C4 + 255) / 256, RC);
  colminmax_kernel<<<grid1, 256, 0, stream>>>((const floatx4*)x, pmax, pmin);
  fold_kernel<<<(PCOLS + 255) / 256, 256, 0, stream>>>(pmax, pmin, Mx, Mn);
  dim3 grid3(SPL, NLENS);
  md_kernel<<<grid3, 256, 0, stream>>>(x, Mx, Mn, mdpart);
  fin_kernel<<<1, 64, 0, stream>>>(mdpart, out);
}